// Round 9
// baseline (451.256 us; speedup 1.0000x reference)
//
#include <hip/hip_runtime.h>
#include <math.h>

// ---------------- dims ----------------
// T=S=48, H=250, EMB=300, gates=1000, 13 sim planes, convnet 48->24->12->6->3->1

typedef __attribute__((ext_vector_type(2))) _Float16 h2f;
typedef unsigned long long u64;

// workspace layout (floats)
#define OFF_XW    0            // 4*48*1000 = 192000 (bias pre-folded)
#define OFF_HS    192000       // 4*48*250  = 48000
#define OFF_SC    240000       // 13*2304 = 29952
#define OFF_BUFA  269952       // 73728 (conv1 out 128x24x24; conv3 out; conv5 out)
#define OFF_BUFB  343680       // 23616 (conv2 out 164x12x12; conv4 out)
#define OFF_WIHT  367296       // 600000 fp32 transposed w_ih [2][300][1000]
#define OFF_WPK   967296       // 250000 u32: packed fp16 w_hh [2][125][1000]
#define OFF_SEL   1217296      // 2*2304 bytes = 1152 floats
// total ~1218448 floats (~4.9 MB)

__device__ __forceinline__ float sigf(float x) { return 1.f / (1.f + expf(-x)); }

#if __has_builtin(__builtin_amdgcn_fdot2)
__device__ __forceinline__ float dot2(h2f a, h2f b, float c) {
    return __builtin_amdgcn_fdot2(a, b, c, false);
}
#else
__device__ __forceinline__ float dot2(h2f a, h2f b, float c) {
    return c + (float)a.x * (float)b.x + (float)a.y * (float)b.y;
}
#endif

// ---------------- 0a) tiled transpose w_ih: [1000][300] -> [300][1000] ----------------
// grid dim3(32, 10, 2), block dim3(32, 32)
__global__ void transpose_wih_kernel(const float* __restrict__ wf, const float* __restrict__ wb,
                                     float* __restrict__ wT)
{
    __shared__ float tile[32][33];
    int dir = blockIdx.z;
    const float* w = dir ? wb : wf;

    int j = blockIdx.x * 32 + threadIdx.y;   // row of w (0..999)
    int k = blockIdx.y * 32 + threadIdx.x;   // col of w (0..299)
    if (j < 1000 && k < 300)
        tile[threadIdx.y][threadIdx.x] = w[(size_t)j * 300 + k];
    __syncthreads();

    int ko = blockIdx.y * 32 + threadIdx.y;
    int jo = blockIdx.x * 32 + threadIdx.x;
    if (ko < 300 && jo < 1000)
        wT[(size_t)dir * 300000 + (size_t)ko * 1000 + jo] = tile[threadIdx.x][threadIdx.y];
}

// ---------------- 0b) pack w_hh to fp16 [dir][pair][row] for lane-coalesced lstm loads ----------------
// grid 2000 = (dir,row j); block 128 (125 active): reads row-contiguous, writes scattered
__global__ void pack_whh_kernel(const float* __restrict__ wf, const float* __restrict__ wb,
                                unsigned int* __restrict__ wpk)
{
    int dir = blockIdx.x / 1000;
    int j   = blockIdx.x % 1000;
    const float* w = (dir ? wb : wf) + (size_t)j * 250;
    int p = threadIdx.x;
    if (p < 125) {
        float2 v = *(const float2*)(w + 2 * p);
        h2f pv; pv.x = (_Float16)v.x; pv.y = (_Float16)v.y;
        wpk[(size_t)dir * 125000 + (size_t)p * 1000 + j] = *(unsigned int*)&pv;
    }
}

// ---------------- 1) embedding gather + x @ w_ih^T + bias (coalesced via wT) ----------------
__global__ void embed_xw_kernel(const int* __restrict__ x1, const int* __restrict__ x2,
                                const float* __restrict__ emb, const float* __restrict__ wT,
                                const float* __restrict__ b_f, const float* __restrict__ b_b,
                                float* __restrict__ xW)
{
    int t = blockIdx.x % 48;
    int m = blockIdx.x / 48;
    const int* x = (m < 2) ? x1 : x2;
    const float* w = wT + (size_t)(m & 1) * 300000;
    const float* bias = (m & 1) ? b_b : b_f;

    __shared__ float e[300];
    int row = x[t];
    for (int k = threadIdx.x; k < 300; k += 512)
        e[k] = emb[(size_t)row * 300 + k];
    __syncthreads();

    int j0 = threadIdx.x;
    int j1 = threadIdx.x + 512;
    int j1c = j1 < 1000 ? j1 : 999;
    float a0 = 0.f, a1 = 0.f;
    #pragma unroll 4
    for (int k = 0; k < 300; ++k) {
        float ek = e[k];
        const float* wr = w + (size_t)k * 1000;
        a0 += ek * wr[j0];
        a1 += ek * wr[j1c];
    }
    float* out = xW + ((size_t)m * 48 + t) * 1000;
    out[j0] = a0 + bias[j0];
    if (j1 < 1000) out[j1] = a1 + bias[j1];
}

// ---------------- 2) LSTM: one block per (seq,dir), 512 threads = 8 waves ----------------
// REGISTER LAW (learned r4-r6): per-thread demand must be <= ~245 arch VGPRs, else scratch.
// Thread t<500 owns rows {t, t+500}: t<250 -> (i,g) of unit t; t>=250 -> (f,o) of unit t-250.
// Weight pairs 0..11 in LDS (48KB, [pair][row] u32, conflict-free); pairs 12..124 in regs (226).
// 2 intra-CU barriers/step; c in register; h packed fp16 single-buffer LDS.
__global__ void __launch_bounds__(512, 1) lstm_kernel(
    const float* __restrict__ xW, const unsigned int* __restrict__ wpk,
    float* __restrict__ hs)
{
    int m   = blockIdx.x;           // 0: s1 fwd, 1: s1 bwd, 2: s2 fwd, 3: s2 bwd
    int dir = m & 1;
    const unsigned int* wp = wpk + (size_t)dir * 125000;
    const float* xw = xW + (size_t)m * 48000;
    float* out      = hs + (size_t)m * 12000;

    int t = threadIdx.x;
    bool active = t < 500;
    int r0 = t, r1 = t + 500;

    __shared__ __align__(16) unsigned int hp[128];     // packed fp16 h pairs
    __shared__ float fo_lds[500];                      // fv [0..249], ov [250..499]
    __shared__ unsigned int wl[12 * 1000];             // weight pairs 0..11, [pair][row]

    // LDS weights: pairs 0..11 = first 12000 u32 of this direction's wpk
    for (int idx = t; idx < 12000; idx += 512)
        wl[idx] = wp[idx];

    // register weights: pairs 12..124 (113 per row, 226 total) - lane-coalesced
    h2f w0r[113], w1r[113];
    if (active) {
        #pragma unroll
        for (int p = 0; p < 113; ++p) {
            unsigned int a = wp[(p + 12) * 1000 + r0];
            unsigned int b = wp[(p + 12) * 1000 + r1];
            w0r[p] = *(h2f*)&a;
            w1r[p] = *(h2f*)&b;
        }
    }
    if (t < 128) hp[t] = 0u;
    float c = 0.f;
    __syncthreads();

    for (int step = 0; step < 48; ++step) {
        int tt = dir ? 47 - step : step;
        float a0 = 0.f, a1 = 0.f;
        if (active) {
            const float* xwt = xw + tt * 1000;
            a0 = xwt[r0];
            a1 = xwt[r1];
            const uint4* hp4 = (const uint4*)hp;
            // pairs 0..11 from LDS
            #pragma unroll
            for (int q = 0; q < 3; ++q) {
                uint4 hq = hp4[q];
                h2f h0 = *(h2f*)&hq.x, h1 = *(h2f*)&hq.y, h2v = *(h2f*)&hq.z, h3 = *(h2f*)&hq.w;
                unsigned int u00 = wl[(4 * q + 0) * 1000 + r0], u01 = wl[(4 * q + 0) * 1000 + r1];
                unsigned int u10 = wl[(4 * q + 1) * 1000 + r0], u11 = wl[(4 * q + 1) * 1000 + r1];
                unsigned int u20 = wl[(4 * q + 2) * 1000 + r0], u21 = wl[(4 * q + 2) * 1000 + r1];
                unsigned int u30 = wl[(4 * q + 3) * 1000 + r0], u31 = wl[(4 * q + 3) * 1000 + r1];
                a0 = dot2(*(h2f*)&u00, h0, a0);  a1 = dot2(*(h2f*)&u01, h0, a1);
                a0 = dot2(*(h2f*)&u10, h1, a0);  a1 = dot2(*(h2f*)&u11, h1, a1);
                a0 = dot2(*(h2f*)&u20, h2v, a0); a1 = dot2(*(h2f*)&u21, h2v, a1);
                a0 = dot2(*(h2f*)&u30, h3, a0);  a1 = dot2(*(h2f*)&u31, h3, a1);
            }
            // pairs 12..123 from regs (28 groups of 4)
            #pragma unroll
            for (int jj = 3; jj < 31; ++jj) {
                uint4 hq = hp4[jj];
                h2f h0 = *(h2f*)&hq.x, h1 = *(h2f*)&hq.y, h2v = *(h2f*)&hq.z, h3 = *(h2f*)&hq.w;
                int p = 4 * jj - 12;
                a0 = dot2(w0r[p + 0], h0, a0);  a1 = dot2(w1r[p + 0], h0, a1);
                a0 = dot2(w0r[p + 1], h1, a0);  a1 = dot2(w1r[p + 1], h1, a1);
                a0 = dot2(w0r[p + 2], h2v, a0); a1 = dot2(w1r[p + 2], h2v, a1);
                a0 = dot2(w0r[p + 3], h3, a0);  a1 = dot2(w1r[p + 3], h3, a1);
            }
            {   // tail pair 124 -> reg index 112
                unsigned int hq = hp[124];
                h2f hv = *(h2f*)&hq;
                a0 = dot2(w0r[112], hv, a0);
                a1 = dot2(w1r[112], hv, a1);
            }
            if (t >= 250) {                    // f,o owner: pre-apply sigmoids, publish
                fo_lds[t - 250] = sigf(a0);            // fv of unit t-250
                fo_lds[250 + (t - 250)] = sigf(a1);    // ov of unit t-250
            }
        }
        __syncthreads();
        if (t < 250) {
            float iv = sigf(a0);
            float gv = tanhf(a1);
            float fv = fo_lds[t];
            float ov = fo_lds[250 + t];
            c = fv * c + iv * gv;
            float hn = ov * tanhf(c);
            out[tt * 250 + t] = hn;
            float hi = __shfl_down(hn, 1);
            if (!(t & 1)) {                    // (even,even+1) stay within a wave
                h2f pv; pv.x = (_Float16)hn; pv.y = (_Float16)hi;
                hp[t >> 1] = *(unsigned int*)&pv;
            }
        }
        __syncthreads();
    }
}

// ---------------- 3) similarity cube with inline norms: 13 x 48 x 48 ----------------
__global__ void sim_kernel(const float* __restrict__ hs, float* __restrict__ sc)
{
    int p = blockIdx.x;
    int i = p / 48, jj = p % 48;
    const float* h1f = hs + ((size_t)0 * 48 + i) * 250;
    const float* h1b = hs + ((size_t)1 * 48 + i) * 250;
    const float* h2f = hs + ((size_t)2 * 48 + jj) * 250;
    const float* h2b = hs + ((size_t)3 * 48 + jj) * 250;
    int lane = threadIdx.x;
    float dff = 0.f, dbb = 0.f, dfb = 0.f, dbf = 0.f;
    float sfa = 0.f, sba = 0.f, caa = 0.f;
    float sfb = 0.f, sbb = 0.f, cbb = 0.f;
    for (int k = lane; k < 250; k += 64) {
        float af = h1f[k], ab = h1b[k], bf = h2f[k], bb = h2b[k];
        dff += af * bf; dbb += ab * bb; dfb += af * bb; dbf += ab * bf;
        sfa += af * af; sba += ab * ab; caa += af * ab;
        sfb += bf * bf; sbb += bb * bb; cbb += bf * bb;
    }
    #pragma unroll
    for (int o = 32; o; o >>= 1) {
        dff += __shfl_down(dff, o); dbb += __shfl_down(dbb, o);
        dfb += __shfl_down(dfb, o); dbf += __shfl_down(dbf, o);
        sfa += __shfl_down(sfa, o); sba += __shfl_down(sba, o);
        caa += __shfl_down(caa, o);
        sfb += __shfl_down(sfb, o); sbb += __shfl_down(sbb, o);
        cbb += __shfl_down(cbb, o);
    }
    if (lane == 0) {
        #define EMIT(basep, dotv, sa2, sb2)                                 \
        {                                                                   \
            float na = sqrtf(sa2), nbv = sqrtf(sb2);                        \
            float dv = (dotv);                                              \
            sc[(basep) * 2304 + p] = dv;                                    \
            sc[((basep) + 1) * 2304 + p] = dv / (na * nbv + 1e-8f);         \
            float d2 = fmaxf(na * na + nbv * nbv - 2.f * dv, 1e-12f);       \
            sc[((basep) + 2) * 2304 + p] = sqrtf(d2);                       \
        }
        EMIT(0, dff + dbb, sfa + sba, sfb + sbb);
        EMIT(3, dff, sfa, sfb);
        EMIT(6, dbb, sba, sbb);
        EMIT(9, dff + dfb + dbf + dbb, sfa + sba + 2.f * caa, sfb + sbb + 2.f * cbb);
        #undef EMIT
        // plane 12 is identically zero and skipped by conv1
    }
}

// ---------------- 4) greedy top-k via full bitonic sort (replaces 96x iterative argmax) ----------------
// 2 blocks (one per plane), 256 threads. Key = (ordered_float<<32)|(4095-idx):
// descending sort == top_k order (value desc, index asc on ties). Then thread 0
// does the sequential greedy marking over the first 96 sorted keys.
__global__ void greedy_kernel(const float* __restrict__ sc, unsigned char* __restrict__ sel)
{
    __shared__ u64 keys[4096];
    __shared__ unsigned char selL[2304];
    int tid = threadIdx.x;
    int plane = 10 + blockIdx.x;

    for (int i = tid; i < 4096; i += 256) {
        u64 key = 0;                                   // pads sort last
        if (i < 2304) {
            unsigned int u = __float_as_uint(sc[plane * 2304 + i]);
            unsigned int ord = (u & 0x80000000u) ? ~u : (u | 0x80000000u);
            key = ((u64)ord << 32) | (unsigned int)(4095 - i);
            selL[i] = 0;
        }
        keys[i] = key;
    }
    __syncthreads();

    // bitonic sort, descending
    for (int k = 2; k <= 4096; k <<= 1) {
        for (int j = k >> 1; j > 0; j >>= 1) {
            for (int i = tid; i < 4096; i += 256) {
                int ixj = i ^ j;
                if (ixj > i) {
                    u64 a = keys[i], b = keys[ixj];
                    bool up = ((i & k) == 0);          // descending region
                    if (up ? (a < b) : (a > b)) { keys[i] = b; keys[ixj] = a; }
                }
            }
            __syncthreads();
        }
    }

    if (tid == 0) {
        u64 m1 = 0, m2 = 0;
        for (int q = 0; q < 96; ++q) {
            int idx = 4095 - (int)(keys[q] & 0xFFFFFFFFu);
            int p1 = idx / 48, p2 = idx % 48;
            if (!((m1 >> p1) & 1) && !((m2 >> p2) & 1)) {
                m1 |= 1ull << p1;
                m2 |= 1ull << p2;
                selL[idx] = 1;
            }
        }
    }
    __syncthreads();
    for (int i = tid; i < 2304; i += 256)
        sel[blockIdx.x * 2304 + i] = selL[i];
}

// ---------------- 5) conv1 (12 planes ->128, 48x48) + fused focus mask + relu + pool2x2 ----------------
// grid 128*9, block 256 (16x16 tile)
__global__ void conv1_pool_kernel(const float* __restrict__ sc, const unsigned char* __restrict__ sel,
                                  const float* __restrict__ w, const float* __restrict__ bias,
                                  float* __restrict__ out)
{
    __shared__ float tile[256];
    int co  = blockIdx.x / 9;
    int tl  = blockIdx.x % 9;
    int ty0 = (tl / 3) * 16, tx0 = (tl % 3) * 16;
    int tx = threadIdx.x % 16, ty = threadIdx.x / 16;
    int x = tx0 + tx, y = ty0 + ty;

    float mv[9];
    #pragma unroll
    for (int ky = 0; ky < 3; ++ky) {
        int iy = y + ky - 1;
        #pragma unroll
        for (int kx = 0; kx < 3; ++kx) {
            int ix = x + kx - 1;
            float mm = 0.f;
            if (iy >= 0 && iy < 48 && ix >= 0 && ix < 48) {
                int p = iy * 48 + ix;
                mm = (sel[p] | sel[2304 + p]) ? 1.0f : 0.1f;
            }
            mv[ky * 3 + kx] = mm;
        }
    }

    float acc = bias[co];
    const float* wco = w + (size_t)co * 13 * 9;
    for (int ci = 0; ci < 12; ++ci) {
        const float* inp = sc + (size_t)ci * 2304;
        const float* wp = wco + ci * 9;
        #pragma unroll
        for (int ky = 0; ky < 3; ++ky) {
            int iy = y + ky - 1;
            if (iy < 0 || iy >= 48) continue;
            #pragma unroll
            for (int kx = 0; kx < 3; ++kx) {
                int ix = x + kx - 1;
                if (ix < 0 || ix >= 48) continue;
                acc += inp[iy * 48 + ix] * mv[ky * 3 + kx] * wp[ky * 3 + kx];
            }
        }
    }
    tile[threadIdx.x] = acc > 0.f ? acc : 0.f;
    __syncthreads();
    if (threadIdx.x < 64) {
        int py = threadIdx.x / 8, px = threadIdx.x % 8;
        float a = tile[(py * 2) * 16 + px * 2];
        float b = tile[(py * 2) * 16 + px * 2 + 1];
        float cc = tile[(py * 2 + 1) * 16 + px * 2];
        float d = tile[(py * 2 + 1) * 16 + px * 2 + 1];
        float best = fmaxf(fmaxf(a, b), fmaxf(cc, d));
        out[(size_t)co * 576 + (ty0 / 2 + py) * 24 + (tx0 / 2 + px)] = best;
    }
}

// ---------------- 6) Cin-split conv3x3 + relu + pool ----------------
// grid (Cout, tilesY, tilesX); block = P*CC threads, P = tileH*tileW
__global__ void conv_cs_kernel(const float* __restrict__ in, const float* __restrict__ w,
                               const float* __restrict__ bias, float* __restrict__ out,
                               int Cin, int H, int W, int tileH, int tileW,
                               int cpc, int CC, int pk, int ps, int PHf, int PWf)
{
    extern __shared__ float sm[];          // P*CC partials + P results
    int P = tileH * tileW;
    int co = blockIdx.x;
    int ty0 = blockIdx.y * tileH, tx0 = blockIdx.z * tileW;
    int t = threadIdx.x;
    int pix = t % P, chunk = t / P;
    int y = ty0 + pix / tileW, x = tx0 + pix % tileW;
    int c0 = chunk * cpc;
    int c1 = c0 + cpc; if (c1 > Cin) c1 = Cin;

    float acc = 0.f;
    const float* wco = w + (size_t)co * Cin * 9;
    for (int ci = c0; ci < c1; ++ci) {
        const float* inp = in + (size_t)ci * H * W;
        const float* wp = wco + (size_t)ci * 9;
        #pragma unroll
        for (int ky = 0; ky < 3; ++ky) {
            int iy = y + ky - 1;
            if (iy < 0 || iy >= H) continue;
            const float* rowp = inp + iy * W;
            #pragma unroll
            for (int kx = 0; kx < 3; ++kx) {
                int ix = x + kx - 1;
                if (ix < 0 || ix >= W) continue;
                acc += rowp[ix] * wp[ky * 3 + kx];
            }
        }
    }
    sm[t] = acc;
    __syncthreads();
    float* res = sm + P * CC;
    if (chunk == 0) {
        float tot = bias[co];
        for (int cc2 = 0; cc2 < CC; ++cc2) tot += sm[pix + cc2 * P];
        res[pix] = tot > 0.f ? tot : 0.f;
    }
    __syncthreads();
    int pH = (tileH - pk) / ps + 1, pW = (tileW - pk) / ps + 1;
    if (t < pH * pW) {
        int py = t / pW, px = t % pW;
        float best = -INFINITY;
        for (int dy = 0; dy < pk; ++dy)
            for (int dx = 0; dx < pk; ++dx) {
                float v = res[(py * ps + dy) * tileW + (px * ps + dx)];
                best = v > best ? v : best;
            }
        out[((size_t)co * PHf + (ty0 / ps + py)) * PWf + (tx0 / ps + px)] = best;
    }
}

// ---------------- 7) head ----------------
__global__ void head_kernel(const float* __restrict__ feat,
                            const float* __restrict__ dnn_w, const float* __restrict__ dnn_b,
                            const float* __restrict__ out_w, const float* __restrict__ out_b,
                            float* __restrict__ out)
{
    __shared__ float y[128];
    __shared__ float logits[5];
    int j = threadIdx.x;
    float acc = dnn_b[j];
    for (int k = 0; k < 128; ++k) acc += feat[k] * dnn_w[j * 128 + k];
    y[j] = acc > 0.f ? acc : 0.f;
    __syncthreads();
    if (j < 5) {
        float a = out_b[j];
        for (int k = 0; k < 128; ++k) a += y[k] * out_w[j * 128 + k];
        logits[j] = a;
    }
    __syncthreads();
    if (j == 0) {
        float m = logits[0];
        for (int l = 1; l < 5; ++l) m = fmaxf(m, logits[l]);
        float s = 0.f;
        for (int l = 0; l < 5; ++l) s += expf(logits[l] - m);
        float lse = logf(s);
        for (int l = 0; l < 5; ++l) out[l] = logits[l] - m - lse;
    }
}

extern "C" void kernel_launch(void* const* d_in, const int* in_sizes, int n_in,
                              void* d_out, int out_size, void* d_ws, size_t ws_size,
                              hipStream_t stream)
{
    const int*   x1     = (const int*)d_in[0];
    const int*   x2     = (const int*)d_in[1];
    const float* emb    = (const float*)d_in[2];
    const float* w_ih_f = (const float*)d_in[3];
    const float* w_hh_f = (const float*)d_in[4];
    const float* b_f    = (const float*)d_in[5];
    const float* w_ih_b = (const float*)d_in[6];
    const float* w_hh_b = (const float*)d_in[7];
    const float* b_b    = (const float*)d_in[8];
    const float* c1_w   = (const float*)d_in[9];
    const float* c1_b   = (const float*)d_in[10];
    const float* c2_w   = (const float*)d_in[11];
    const float* c2_b   = (const float*)d_in[12];
    const float* c3_w   = (const float*)d_in[13];
    const float* c3_b   = (const float*)d_in[14];
    const float* c4_w   = (const float*)d_in[15];
    const float* c4_b   = (const float*)d_in[16];
    const float* c5_w   = (const float*)d_in[17];
    const float* c5_b   = (const float*)d_in[18];
    const float* dnn_w  = (const float*)d_in[19];
    const float* dnn_b  = (const float*)d_in[20];
    const float* out_w  = (const float*)d_in[21];
    const float* out_b  = (const float*)d_in[22];

    float* ws    = (float*)d_ws;
    float* xW    = ws + OFF_XW;
    float* hsb   = ws + OFF_HS;
    float* sc    = ws + OFF_SC;
    float* bufA  = ws + OFF_BUFA;
    float* bufB  = ws + OFF_BUFB;
    float* wihT  = ws + OFF_WIHT;
    unsigned int* wpk = (unsigned int*)(ws + OFF_WPK);
    unsigned char* sel = (unsigned char*)(ws + OFF_SEL);
    float* outp  = (float*)d_out;

    transpose_wih_kernel<<<dim3(32, 10, 2), dim3(32, 32), 0, stream>>>(w_ih_f, w_ih_b, wihT);
    pack_whh_kernel<<<2000, 128, 0, stream>>>(w_hh_f, w_hh_b, wpk);
    embed_xw_kernel<<<192, 512, 0, stream>>>(x1, x2, emb, wihT, b_f, b_b, xW);
    lstm_kernel<<<4, 512, 0, stream>>>(xW, wpk, hsb);
    sim_kernel<<<2304, 64, 0, stream>>>(hsb, sc);
    greedy_kernel<<<2, 256, 0, stream>>>(sc, sel);

    // conv stack: 13x48x48 ->128x24x24 ->164x12x12 ->192x6x6 ->192x3x3 ->128
    conv1_pool_kernel<<<128 * 9, 256, 0, stream>>>(sc, sel, c1_w, c1_b, bufA);
    conv_cs_kernel<<<dim3(164, 2, 2), 576, (576 + 144) * 4, stream>>>(
        bufA, c2_w, c2_b, bufB, 128, 24, 24, 12, 12, 32, 4, 2, 2, 12, 12);
    conv_cs_kernel<<<dim3(192, 1, 1), 576, (576 + 144) * 4, stream>>>(
        bufB, c3_w, c3_b, bufA, 164, 12, 12, 12, 12, 41, 4, 2, 2, 6, 6);
    conv_cs_kernel<<<dim3(192, 1, 1), 576, (576 + 36) * 4, stream>>>(
        bufA, c4_w, c4_b, bufB, 192, 6, 6, 6, 6, 12, 16, 2, 2, 3, 3);
    conv_cs_kernel<<<dim3(128, 1, 1), 576, (576 + 9) * 4, stream>>>(
        bufB, c5_w, c5_b, bufA, 192, 3, 3, 3, 3, 3, 64, 3, 1, 1, 1);

    head_kernel<<<1, 128, 0, stream>>>(bufA, dnn_w, dnn_b, out_w, out_b, outp);
}

// Round 10
// 348.421 us; speedup vs baseline: 1.2951x; 1.2951x over previous
//
#include <hip/hip_runtime.h>
#include <math.h>

// ---------------- dims ----------------
// T=S=48, H=250, EMB=300, gates=1000, 13 sim planes, convnet 48->24->12->6->3->1

typedef __attribute__((ext_vector_type(2))) _Float16 h2f;
typedef unsigned long long u64;

// workspace layout (floats)
#define OFF_XW    0            // 4*48*1000 = 192000 (bias pre-folded)
#define OFF_HS    192000       // 4*48*250  = 48000
#define OFF_SC    240000       // 13*2304 = 29952
#define OFF_BUFA  269952       // 73728 (conv1 out 128x24x24; conv3 out; conv5 out)
#define OFF_BUFB  343680       // 23616 (conv2 out 164x12x12; conv4 out)
#define OFF_WIHT  367296       // 600000 fp32 transposed w_ih [2][300][1000]
#define OFF_WPK   967296       // 250000 u32: packed fp16 w_hh [2][125][1000]
#define OFF_SEL   1217296      // 2*2304 bytes = 1152 floats
// total ~1218448 floats (~4.9 MB)

__device__ __forceinline__ float sigf(float x) { return 1.f / (1.f + expf(-x)); }

#if __has_builtin(__builtin_amdgcn_fdot2)
__device__ __forceinline__ float dot2(h2f a, h2f b, float c) {
    return __builtin_amdgcn_fdot2(a, b, c, false);
}
#else
__device__ __forceinline__ float dot2(h2f a, h2f b, float c) {
    return c + (float)a.x * (float)b.x + (float)a.y * (float)b.y;
}
#endif

// ---------------- 0a) tiled transpose w_ih: [1000][300] -> [300][1000] ----------------
// grid dim3(32, 10, 2), block dim3(32, 32)
__global__ void transpose_wih_kernel(const float* __restrict__ wf, const float* __restrict__ wb,
                                     float* __restrict__ wT)
{
    __shared__ float tile[32][33];
    int dir = blockIdx.z;
    const float* w = dir ? wb : wf;

    int j = blockIdx.x * 32 + threadIdx.y;   // row of w (0..999)
    int k = blockIdx.y * 32 + threadIdx.x;   // col of w (0..299)
    if (j < 1000 && k < 300)
        tile[threadIdx.y][threadIdx.x] = w[(size_t)j * 300 + k];
    __syncthreads();

    int ko = blockIdx.y * 32 + threadIdx.y;
    int jo = blockIdx.x * 32 + threadIdx.x;
    if (ko < 300 && jo < 1000)
        wT[(size_t)dir * 300000 + (size_t)ko * 1000 + jo] = tile[threadIdx.x][threadIdx.y];
}

// ---------------- 0b) pack w_hh to fp16 [dir][pair][row] for lane-coalesced lstm loads ----------------
// grid 2000 = (dir,row j); block 128 (125 active): reads row-contiguous, writes scattered
__global__ void pack_whh_kernel(const float* __restrict__ wf, const float* __restrict__ wb,
                                unsigned int* __restrict__ wpk)
{
    int dir = blockIdx.x / 1000;
    int j   = blockIdx.x % 1000;
    const float* w = (dir ? wb : wf) + (size_t)j * 250;
    int p = threadIdx.x;
    if (p < 125) {
        float2 v = *(const float2*)(w + 2 * p);
        h2f pv; pv.x = (_Float16)v.x; pv.y = (_Float16)v.y;
        wpk[(size_t)dir * 125000 + (size_t)p * 1000 + j] = *(unsigned int*)&pv;
    }
}

// ---------------- 1) embedding gather + x @ w_ih^T + bias (coalesced via wT) ----------------
__global__ void embed_xw_kernel(const int* __restrict__ x1, const int* __restrict__ x2,
                                const float* __restrict__ emb, const float* __restrict__ wT,
                                const float* __restrict__ b_f, const float* __restrict__ b_b,
                                float* __restrict__ xW)
{
    int t = blockIdx.x % 48;
    int m = blockIdx.x / 48;
    const int* x = (m < 2) ? x1 : x2;
    const float* w = wT + (size_t)(m & 1) * 300000;
    const float* bias = (m & 1) ? b_b : b_f;

    __shared__ float e[300];
    int row = x[t];
    for (int k = threadIdx.x; k < 300; k += 512)
        e[k] = emb[(size_t)row * 300 + k];
    __syncthreads();

    int j0 = threadIdx.x;
    int j1 = threadIdx.x + 512;
    int j1c = j1 < 1000 ? j1 : 999;
    float a0 = 0.f, a1 = 0.f;
    #pragma unroll 4
    for (int k = 0; k < 300; ++k) {
        float ek = e[k];
        const float* wr = w + (size_t)k * 1000;
        a0 += ek * wr[j0];
        a1 += ek * wr[j1c];
    }
    float* out = xW + ((size_t)m * 48 + t) * 1000;
    out[j0] = a0 + bias[j0];
    if (j1 < 1000) out[j1] = a1 + bias[j1];
}

// ---------------- 2) LSTM: one block per (seq,dir), 512 threads = 8 waves ----------------
// REGISTER LAW (learned r4-r6): per-thread demand must be <= ~245 arch VGPRs, else scratch.
// Thread t<500 owns rows {t, t+500}: t<250 -> (i,g) of unit t; t>=250 -> (f,o) of unit t-250.
// Weight pairs 0..11 in LDS (48KB, [pair][row] u32, conflict-free); pairs 12..124 in regs (226).
// 2 intra-CU barriers/step; c in register; h packed fp16 single-buffer LDS.
__global__ void __launch_bounds__(512, 1) lstm_kernel(
    const float* __restrict__ xW, const unsigned int* __restrict__ wpk,
    float* __restrict__ hs)
{
    int m   = blockIdx.x;           // 0: s1 fwd, 1: s1 bwd, 2: s2 fwd, 3: s2 bwd
    int dir = m & 1;
    const unsigned int* wp = wpk + (size_t)dir * 125000;
    const float* xw = xW + (size_t)m * 48000;
    float* out      = hs + (size_t)m * 12000;

    int t = threadIdx.x;
    bool active = t < 500;
    int r0 = t, r1 = t + 500;

    __shared__ __align__(16) unsigned int hp[128];     // packed fp16 h pairs
    __shared__ float fo_lds[500];                      // fv [0..249], ov [250..499]
    __shared__ unsigned int wl[12 * 1000];             // weight pairs 0..11, [pair][row]

    // LDS weights: pairs 0..11 = first 12000 u32 of this direction's wpk
    for (int idx = t; idx < 12000; idx += 512)
        wl[idx] = wp[idx];

    // register weights: pairs 12..124 (113 per row, 226 total) - lane-coalesced
    h2f w0r[113], w1r[113];
    if (active) {
        #pragma unroll
        for (int p = 0; p < 113; ++p) {
            unsigned int a = wp[(p + 12) * 1000 + r0];
            unsigned int b = wp[(p + 12) * 1000 + r1];
            w0r[p] = *(h2f*)&a;
            w1r[p] = *(h2f*)&b;
        }
    }
    if (t < 128) hp[t] = 0u;
    float c = 0.f;
    __syncthreads();

    for (int step = 0; step < 48; ++step) {
        int tt = dir ? 47 - step : step;
        float a0 = 0.f, a1 = 0.f;
        if (active) {
            const float* xwt = xw + tt * 1000;
            a0 = xwt[r0];
            a1 = xwt[r1];
            const uint4* hp4 = (const uint4*)hp;
            // pairs 0..11 from LDS
            #pragma unroll
            for (int q = 0; q < 3; ++q) {
                uint4 hq = hp4[q];
                h2f h0 = *(h2f*)&hq.x, h1 = *(h2f*)&hq.y, h2v = *(h2f*)&hq.z, h3 = *(h2f*)&hq.w;
                unsigned int u00 = wl[(4 * q + 0) * 1000 + r0], u01 = wl[(4 * q + 0) * 1000 + r1];
                unsigned int u10 = wl[(4 * q + 1) * 1000 + r0], u11 = wl[(4 * q + 1) * 1000 + r1];
                unsigned int u20 = wl[(4 * q + 2) * 1000 + r0], u21 = wl[(4 * q + 2) * 1000 + r1];
                unsigned int u30 = wl[(4 * q + 3) * 1000 + r0], u31 = wl[(4 * q + 3) * 1000 + r1];
                a0 = dot2(*(h2f*)&u00, h0, a0);  a1 = dot2(*(h2f*)&u01, h0, a1);
                a0 = dot2(*(h2f*)&u10, h1, a0);  a1 = dot2(*(h2f*)&u11, h1, a1);
                a0 = dot2(*(h2f*)&u20, h2v, a0); a1 = dot2(*(h2f*)&u21, h2v, a1);
                a0 = dot2(*(h2f*)&u30, h3, a0);  a1 = dot2(*(h2f*)&u31, h3, a1);
            }
            // pairs 12..123 from regs (28 groups of 4)
            #pragma unroll
            for (int jj = 3; jj < 31; ++jj) {
                uint4 hq = hp4[jj];
                h2f h0 = *(h2f*)&hq.x, h1 = *(h2f*)&hq.y, h2v = *(h2f*)&hq.z, h3 = *(h2f*)&hq.w;
                int p = 4 * jj - 12;
                a0 = dot2(w0r[p + 0], h0, a0);  a1 = dot2(w1r[p + 0], h0, a1);
                a0 = dot2(w0r[p + 1], h1, a0);  a1 = dot2(w1r[p + 1], h1, a1);
                a0 = dot2(w0r[p + 2], h2v, a0); a1 = dot2(w1r[p + 2], h2v, a1);
                a0 = dot2(w0r[p + 3], h3, a0);  a1 = dot2(w1r[p + 3], h3, a1);
            }
            {   // tail pair 124 -> reg index 112
                unsigned int hq = hp[124];
                h2f hv = *(h2f*)&hq;
                a0 = dot2(w0r[112], hv, a0);
                a1 = dot2(w1r[112], hv, a1);
            }
            if (t >= 250) {                    // f,o owner: pre-apply sigmoids, publish
                fo_lds[t - 250] = sigf(a0);            // fv of unit t-250
                fo_lds[250 + (t - 250)] = sigf(a1);    // ov of unit t-250
            }
        }
        __syncthreads();
        if (t < 250) {
            float iv = sigf(a0);
            float gv = tanhf(a1);
            float fv = fo_lds[t];
            float ov = fo_lds[250 + t];
            c = fv * c + iv * gv;
            float hn = ov * tanhf(c);
            out[tt * 250 + t] = hn;
            float hi = __shfl_down(hn, 1);
            if (!(t & 1)) {                    // (even,even+1) stay within a wave
                h2f pv; pv.x = (_Float16)hn; pv.y = (_Float16)hi;
                hp[t >> 1] = *(unsigned int*)&pv;
            }
        }
        __syncthreads();
    }
}

// ---------------- 3) similarity cube with inline norms: 13 x 48 x 48 ----------------
__global__ void sim_kernel(const float* __restrict__ hs, float* __restrict__ sc)
{
    int p = blockIdx.x;
    int i = p / 48, jj = p % 48;
    const float* h1f = hs + ((size_t)0 * 48 + i) * 250;
    const float* h1b = hs + ((size_t)1 * 48 + i) * 250;
    const float* h2f = hs + ((size_t)2 * 48 + jj) * 250;
    const float* h2b = hs + ((size_t)3 * 48 + jj) * 250;
    int lane = threadIdx.x;
    float dff = 0.f, dbb = 0.f, dfb = 0.f, dbf = 0.f;
    float sfa = 0.f, sba = 0.f, caa = 0.f;
    float sfb = 0.f, sbb = 0.f, cbb = 0.f;
    for (int k = lane; k < 250; k += 64) {
        float af = h1f[k], ab = h1b[k], bf = h2f[k], bb = h2b[k];
        dff += af * bf; dbb += ab * bb; dfb += af * bb; dbf += ab * bf;
        sfa += af * af; sba += ab * ab; caa += af * ab;
        sfb += bf * bf; sbb += bb * bb; cbb += bf * bb;
    }
    #pragma unroll
    for (int o = 32; o; o >>= 1) {
        dff += __shfl_down(dff, o); dbb += __shfl_down(dbb, o);
        dfb += __shfl_down(dfb, o); dbf += __shfl_down(dbf, o);
        sfa += __shfl_down(sfa, o); sba += __shfl_down(sba, o);
        caa += __shfl_down(caa, o);
        sfb += __shfl_down(sfb, o); sbb += __shfl_down(sbb, o);
        cbb += __shfl_down(cbb, o);
    }
    if (lane == 0) {
        #define EMIT(basep, dotv, sa2, sb2)                                 \
        {                                                                   \
            float na = sqrtf(sa2), nbv = sqrtf(sb2);                        \
            float dv = (dotv);                                              \
            sc[(basep) * 2304 + p] = dv;                                    \
            sc[((basep) + 1) * 2304 + p] = dv / (na * nbv + 1e-8f);         \
            float d2 = fmaxf(na * na + nbv * nbv - 2.f * dv, 1e-12f);       \
            sc[((basep) + 2) * 2304 + p] = sqrtf(d2);                       \
        }
        EMIT(0, dff + dbb, sfa + sba, sfb + sbb);
        EMIT(3, dff, sfa, sfb);
        EMIT(6, dbb, sba, sbb);
        EMIT(9, dff + dfb + dbf + dbb, sfa + sba + 2.f * caa, sfb + sbb + 2.f * cbb);
        #undef EMIT
        // plane 12 is identically zero and skipped by conv1
    }
}

// ---------------- 4) greedy top-k: single wave per plane, register-resident sorted runs ----------------
// Each lane holds 36 keys (ord<<32 | (4095-idx)) sorted descending in REGISTERS (static
// indices only - rule #20). 96 pops: shfl_xor butterfly max (no LDS, no barriers);
// winner lane shifts its run; masks m1/m2 replicated in every lane.
__global__ void greedy_kernel(const float* __restrict__ sc, unsigned char* __restrict__ sel)
{
    __shared__ unsigned char selL[2304];
    int lane = threadIdx.x;
    int plane = 10 + blockIdx.x;

    // load 36 keys per lane (coalesced), build order-preserving u64 keys
    u64 v[36];
    #pragma unroll
    for (int q = 0; q < 36; ++q) {
        int i = lane + 64 * q;
        unsigned int u = __float_as_uint(sc[plane * 2304 + i]);
        unsigned int ord = (u & 0x80000000u) ? ~u : (u | 0x80000000u);
        v[q] = ((u64)ord << 32) | (unsigned int)(4095 - i);
        selL[i] = 0;
    }

    // in-register descending bubble sort (fully unrolled, static indices)
    #pragma unroll
    for (int a = 0; a < 35; ++a) {
        #pragma unroll
        for (int b = 0; b < 35 - a; ++b) {
            u64 lo = v[b] < v[b + 1] ? v[b] : v[b + 1];
            u64 hi = v[b] < v[b + 1] ? v[b + 1] : v[b];
            v[b] = hi; v[b + 1] = lo;
        }
    }
    __syncthreads();   // selL init visible (single wave; cheap)

    u64 m1 = 0, m2 = 0;    // bipartite row/col masks, replicated in all lanes
    for (int it = 0; it < 96; ++it) {
        u64 bv = v[0];
        #pragma unroll
        for (int o = 1; o < 64; o <<= 1) {
            u64 ov = __shfl_xor(bv, o);
            if (ov > bv) bv = ov;
        }
        int idx = 4095 - (int)(bv & 0xFFFFFFFFu);
        int p1 = idx / 48, p2 = idx % 48;
        bool ok = !((m1 >> p1) & 1) && !((m2 >> p2) & 1);
        if (ok) { m1 |= 1ull << p1; m2 |= 1ull << p2; }
        if (v[0] == bv) {              // unique keys -> exactly one winner lane
            if (ok) selL[idx] = 1;
            #pragma unroll
            for (int q = 0; q < 35; ++q) v[q] = v[q + 1];
            v[35] = 0;
        }
    }
    __syncthreads();
    for (int q = 0; q < 36; ++q) {
        int i = lane + 64 * q;
        sel[blockIdx.x * 2304 + i] = selL[i];
    }
}

// ---------------- 5) conv1 (12 planes ->128, 48x48) + fused focus mask + relu + pool2x2 ----------------
// grid 128*9, block 256 (16x16 tile)
__global__ void conv1_pool_kernel(const float* __restrict__ sc, const unsigned char* __restrict__ sel,
                                  const float* __restrict__ w, const float* __restrict__ bias,
                                  float* __restrict__ out)
{
    __shared__ float tile[256];
    int co  = blockIdx.x / 9;
    int tl  = blockIdx.x % 9;
    int ty0 = (tl / 3) * 16, tx0 = (tl % 3) * 16;
    int tx = threadIdx.x % 16, ty = threadIdx.x / 16;
    int x = tx0 + tx, y = ty0 + ty;

    float mv[9];
    #pragma unroll
    for (int ky = 0; ky < 3; ++ky) {
        int iy = y + ky - 1;
        #pragma unroll
        for (int kx = 0; kx < 3; ++kx) {
            int ix = x + kx - 1;
            float mm = 0.f;
            if (iy >= 0 && iy < 48 && ix >= 0 && ix < 48) {
                int p = iy * 48 + ix;
                mm = (sel[p] | sel[2304 + p]) ? 1.0f : 0.1f;
            }
            mv[ky * 3 + kx] = mm;
        }
    }

    float acc = bias[co];
    const float* wco = w + (size_t)co * 13 * 9;
    for (int ci = 0; ci < 12; ++ci) {
        const float* inp = sc + (size_t)ci * 2304;
        const float* wp = wco + ci * 9;
        #pragma unroll
        for (int ky = 0; ky < 3; ++ky) {
            int iy = y + ky - 1;
            if (iy < 0 || iy >= 48) continue;
            #pragma unroll
            for (int kx = 0; kx < 3; ++kx) {
                int ix = x + kx - 1;
                if (ix < 0 || ix >= 48) continue;
                acc += inp[iy * 48 + ix] * mv[ky * 3 + kx] * wp[ky * 3 + kx];
            }
        }
    }
    tile[threadIdx.x] = acc > 0.f ? acc : 0.f;
    __syncthreads();
    if (threadIdx.x < 64) {
        int py = threadIdx.x / 8, px = threadIdx.x % 8;
        float a = tile[(py * 2) * 16 + px * 2];
        float b = tile[(py * 2) * 16 + px * 2 + 1];
        float cc = tile[(py * 2 + 1) * 16 + px * 2];
        float d = tile[(py * 2 + 1) * 16 + px * 2 + 1];
        float best = fmaxf(fmaxf(a, b), fmaxf(cc, d));
        out[(size_t)co * 576 + (ty0 / 2 + py) * 24 + (tx0 / 2 + px)] = best;
    }
}

// ---------------- 6) Cin-split conv3x3 + relu + pool ----------------
// grid (Cout, tilesY, tilesX); block = P*CC threads, P = tileH*tileW
__global__ void conv_cs_kernel(const float* __restrict__ in, const float* __restrict__ w,
                               const float* __restrict__ bias, float* __restrict__ out,
                               int Cin, int H, int W, int tileH, int tileW,
                               int cpc, int CC, int pk, int ps, int PHf, int PWf)
{
    extern __shared__ float sm[];          // P*CC partials + P results
    int P = tileH * tileW;
    int co = blockIdx.x;
    int ty0 = blockIdx.y * tileH, tx0 = blockIdx.z * tileW;
    int t = threadIdx.x;
    int pix = t % P, chunk = t / P;
    int y = ty0 + pix / tileW, x = tx0 + pix % tileW;
    int c0 = chunk * cpc;
    int c1 = c0 + cpc; if (c1 > Cin) c1 = Cin;

    float acc = 0.f;
    const float* wco = w + (size_t)co * Cin * 9;
    for (int ci = c0; ci < c1; ++ci) {
        const float* inp = in + (size_t)ci * H * W;
        const float* wp = wco + (size_t)ci * 9;
        #pragma unroll
        for (int ky = 0; ky < 3; ++ky) {
            int iy = y + ky - 1;
            if (iy < 0 || iy >= H) continue;
            const float* rowp = inp + iy * W;
            #pragma unroll
            for (int kx = 0; kx < 3; ++kx) {
                int ix = x + kx - 1;
                if (ix < 0 || ix >= W) continue;
                acc += rowp[ix] * wp[ky * 3 + kx];
            }
        }
    }
    sm[t] = acc;
    __syncthreads();
    float* res = sm + P * CC;
    if (chunk == 0) {
        float tot = bias[co];
        for (int cc2 = 0; cc2 < CC; ++cc2) tot += sm[pix + cc2 * P];
        res[pix] = tot > 0.f ? tot : 0.f;
    }
    __syncthreads();
    int pH = (tileH - pk) / ps + 1, pW = (tileW - pk) / ps + 1;
    if (t < pH * pW) {
        int py = t / pW, px = t % pW;
        float best = -INFINITY;
        for (int dy = 0; dy < pk; ++dy)
            for (int dx = 0; dx < pk; ++dx) {
                float v = res[(py * ps + dy) * tileW + (px * ps + dx)];
                best = v > best ? v : best;
            }
        out[((size_t)co * PHf + (ty0 / ps + py)) * PWf + (tx0 / ps + px)] = best;
    }
}

// ---------------- 7) head ----------------
__global__ void head_kernel(const float* __restrict__ feat,
                            const float* __restrict__ dnn_w, const float* __restrict__ dnn_b,
                            const float* __restrict__ out_w, const float* __restrict__ out_b,
                            float* __restrict__ out)
{
    __shared__ float y[128];
    __shared__ float logits[5];
    int j = threadIdx.x;
    float acc = dnn_b[j];
    for (int k = 0; k < 128; ++k) acc += feat[k] * dnn_w[j * 128 + k];
    y[j] = acc > 0.f ? acc : 0.f;
    __syncthreads();
    if (j < 5) {
        float a = out_b[j];
        for (int k = 0; k < 128; ++k) a += y[k] * out_w[j * 128 + k];
        logits[j] = a;
    }
    __syncthreads();
    if (j == 0) {
        float m = logits[0];
        for (int l = 1; l < 5; ++l) m = fmaxf(m, logits[l]);
        float s = 0.f;
        for (int l = 0; l < 5; ++l) s += expf(logits[l] - m);
        float lse = logf(s);
        for (int l = 0; l < 5; ++l) out[l] = logits[l] - m - lse;
    }
}

extern "C" void kernel_launch(void* const* d_in, const int* in_sizes, int n_in,
                              void* d_out, int out_size, void* d_ws, size_t ws_size,
                              hipStream_t stream)
{
    const int*   x1     = (const int*)d_in[0];
    const int*   x2     = (const int*)d_in[1];
    const float* emb    = (const float*)d_in[2];
    const float* w_ih_f = (const float*)d_in[3];
    const float* w_hh_f = (const float*)d_in[4];
    const float* b_f    = (const float*)d_in[5];
    const float* w_ih_b = (const float*)d_in[6];
    const float* w_hh_b = (const float*)d_in[7];
    const float* b_b    = (const float*)d_in[8];
    const float* c1_w   = (const float*)d_in[9];
    const float* c1_b   = (const float*)d_in[10];
    const float* c2_w   = (const float*)d_in[11];
    const float* c2_b   = (const float*)d_in[12];
    const float* c3_w   = (const float*)d_in[13];
    const float* c3_b   = (const float*)d_in[14];
    const float* c4_w   = (const float*)d_in[15];
    const float* c4_b   = (const float*)d_in[16];
    const float* c5_w   = (const float*)d_in[17];
    const float* c5_b   = (const float*)d_in[18];
    const float* dnn_w  = (const float*)d_in[19];
    const float* dnn_b  = (const float*)d_in[20];
    const float* out_w  = (const float*)d_in[21];
    const float* out_b  = (const float*)d_in[22];

    float* ws    = (float*)d_ws;
    float* xW    = ws + OFF_XW;
    float* hsb   = ws + OFF_HS;
    float* sc    = ws + OFF_SC;
    float* bufA  = ws + OFF_BUFA;
    float* bufB  = ws + OFF_BUFB;
    float* wihT  = ws + OFF_WIHT;
    unsigned int* wpk = (unsigned int*)(ws + OFF_WPK);
    unsigned char* sel = (unsigned char*)(ws + OFF_SEL);
    float* outp  = (float*)d_out;

    transpose_wih_kernel<<<dim3(32, 10, 2), dim3(32, 32), 0, stream>>>(w_ih_f, w_ih_b, wihT);
    pack_whh_kernel<<<2000, 128, 0, stream>>>(w_hh_f, w_hh_b, wpk);
    embed_xw_kernel<<<192, 512, 0, stream>>>(x1, x2, emb, wihT, b_f, b_b, xW);
    lstm_kernel<<<4, 512, 0, stream>>>(xW, wpk, hsb);
    sim_kernel<<<2304, 64, 0, stream>>>(hsb, sc);
    greedy_kernel<<<2, 64, 0, stream>>>(sc, sel);

    // conv stack: 13x48x48 ->128x24x24 ->164x12x12 ->192x6x6 ->192x3x3 ->128
    conv1_pool_kernel<<<128 * 9, 256, 0, stream>>>(sc, sel, c1_w, c1_b, bufA);
    conv_cs_kernel<<<dim3(164, 2, 2), 576, (576 + 144) * 4, stream>>>(
        bufA, c2_w, c2_b, bufB, 128, 24, 24, 12, 12, 32, 4, 2, 2, 12, 12);
    conv_cs_kernel<<<dim3(192, 1, 1), 576, (576 + 144) * 4, stream>>>(
        bufB, c3_w, c3_b, bufA, 164, 12, 12, 12, 12, 41, 4, 2, 2, 6, 6);
    conv_cs_kernel<<<dim3(192, 1, 1), 576, (576 + 36) * 4, stream>>>(
        bufA, c4_w, c4_b, bufB, 192, 6, 6, 6, 6, 12, 16, 2, 2, 3, 3);
    conv_cs_kernel<<<dim3(128, 1, 1), 576, (576 + 9) * 4, stream>>>(
        bufB, c5_w, c5_b, bufA, 192, 3, 3, 3, 3, 3, 64, 3, 1, 1, 1);

    head_kernel<<<1, 128, 0, stream>>>(bufA, dnn_w, dnn_b, out_w, out_b, outp);
}